// Round 1
// baseline (88149.518 us; speedup 1.0000x reference)
//
#include <hip/hip_runtime.h>
#include <hip/hip_fp16.h>
#include <math.h>

#define HN 1024
#define FN 256
#define LN 4096
#define NBLK 256
#define NTHR 512
#define NSLOT (LN - 1)   // 4095 sequential steps

// ws layout (in floats):
//   pg1[2][4096]   : partial gates1 double buffer
//   h2b[2][1024]   : h2 double buffer
//   barrier region : 16 group counters (32-dword spaced) + root + gen + abort
#define WS_PG1 0
#define WS_H2B 8192
#define WS_BAR 10240
// inside bar (unsigned indices): group g at g*32, root at 512, gen at 544, abort at 576

__device__ __forceinline__ float sigm(float x) { return 1.0f / (1.0f + __expf(-x)); }
__device__ __forceinline__ float tanh_f(float x) {
    x = fminf(fmaxf(x, -15.0f), 15.0f);
    float e = __expf(2.0f * x);
    return (e - 1.0f) / (e + 1.0f);
}
__device__ __forceinline__ float aload(const float* p) {
    return __hip_atomic_load(p, __ATOMIC_RELAXED, __HIP_MEMORY_SCOPE_AGENT);
}
__device__ __forceinline__ void astore(float* p, float v) {
    __hip_atomic_store(p, v, __ATOMIC_RELAXED, __HIP_MEMORY_SCOPE_AGENT);
}

__global__ void ws_init(unsigned* bar) {
    int t = threadIdx.x;
    if (t < 16) bar[t * 32] = 0u;   // group counters
    if (t == 16) bar[512] = 0u;     // root
    if (t == 17) bar[544] = 0u;     // generation
    if (t == 18) bar[576] = 0u;     // abort flag
}

// 2-level tree barrier (16 groups x 16 blocks), agent scope, bounded spin.
// Returns false if the grid deadlocked (abort) -> caller bails out.
__device__ __forceinline__ bool gridbar(unsigned* bar, unsigned* s_ok) {
    __syncthreads();  // compiler emits vmcnt(0) drain: all this block's agent stores visible
    if (threadIdx.x == 0) {
        unsigned* grp   = bar + ((blockIdx.x >> 4) * 32);
        unsigned* root  = bar + 512;
        unsigned* gen   = bar + 544;
        unsigned* abo   = bar + 576;
        unsigned ok = 1u;
        unsigned g = __hip_atomic_load(gen, __ATOMIC_RELAXED, __HIP_MEMORY_SCOPE_AGENT);
        unsigned a = __hip_atomic_fetch_add(grp, 1u, __ATOMIC_ACQ_REL, __HIP_MEMORY_SCOPE_AGENT);
        if (a == 15u) {
            __hip_atomic_store(grp, 0u, __ATOMIC_RELAXED, __HIP_MEMORY_SCOPE_AGENT);
            unsigned r = __hip_atomic_fetch_add(root, 1u, __ATOMIC_ACQ_REL, __HIP_MEMORY_SCOPE_AGENT);
            if (r == 15u) {
                __hip_atomic_store(root, 0u, __ATOMIC_RELAXED, __HIP_MEMORY_SCOPE_AGENT);
                __hip_atomic_store(gen, g + 1u, __ATOMIC_RELEASE, __HIP_MEMORY_SCOPE_AGENT);
            }
        }
        unsigned it = 0;
        while (__hip_atomic_load(gen, __ATOMIC_ACQUIRE, __HIP_MEMORY_SCOPE_AGENT) == g) {
            __builtin_amdgcn_s_sleep(1);
            if (((++it) & 1023u) == 0u) {
                if (__hip_atomic_load(abo, __ATOMIC_RELAXED, __HIP_MEMORY_SCOPE_AGENT) != 0u) { ok = 0u; break; }
                if (it > (4u << 20)) {
                    __hip_atomic_store(abo, 1u, __ATOMIC_RELAXED, __HIP_MEMORY_SCOPE_AGENT);
                    ok = 0u; break;
                }
            }
        }
        *s_ok = ok;
    }
    __syncthreads();
    return *s_ok != 0u;
}

__global__ __launch_bounds__(NTHR)
void lstm_main(const float* __restrict__ feat, const float* __restrict__ tgt,
               const float* __restrict__ Wih1, const float* __restrict__ bih1,
               const float* __restrict__ Whh1, const float* __restrict__ bhh1,
               const float* __restrict__ Wih2, const float* __restrict__ bih2,
               const float* __restrict__ Whh2, const float* __restrict__ bhh2,
               const float* __restrict__ Wout, const float* __restrict__ bout,
               float* __restrict__ out, float* __restrict__ ws)
{
    // block b owns units j in [4b, 4b+4) of layer1 and layer2.
    // local row lr = g*4 + ui  (g = gate 0..3 in i,f,g,o order, ui = unit 0..3)
    __shared__ __half w1f[16][FN];   // W_ih1[:, :256] rows            8 KB
    __shared__ __half w1h[16][HN];   // W_hh1 rows                    32 KB
    __shared__ __half w2i[16][HN];   // W_ih2 rows                    32 KB
    __shared__ __half w2h[16][HN];   // W_hh2 rows                    32 KB
    __shared__ __half wcol[4 * HN];  // W_ih1[:, 256] (p column)       8 KB
    __shared__ float  wout_s[HN];    //                                4 KB
    __shared__ float  h1p[32 * 33];  // h1, chunk-padded (32 floats + 1 pad)
    __shared__ float  h2p[32 * 33];
    __shared__ float  f_p[32 * 9];   // feature row, chunks of 8 + 1 pad
    __shared__ float  b1s[16], b2s[16], g2s[16];
    __shared__ float  rsum[NTHR / 64];
    __shared__ float  bouts;
    __shared__ unsigned s_ok;

    const int tid = threadIdx.x;
    const int b4  = blockIdx.x * 4;
    float* pg1buf = ws + WS_PG1;
    float* h2buf  = ws + WS_H2B;
    unsigned* bar = (unsigned*)(ws + WS_BAR);

    // ---------------- prologue: stage weights into LDS (fp16) ----------------
    for (int e = tid; e < 16 * FN; e += NTHR) {
        int lr = e >> 8, c = e & (FN - 1);
        int gr = (lr >> 2) * HN + b4 + (lr & 3);
        w1f[lr][c] = __float2half(Wih1[gr * (FN + 1) + c]);
    }
    for (int e = tid; e < 16 * HN; e += NTHR) {
        int lr = e >> 10, c = e & (HN - 1);
        int gr = (lr >> 2) * HN + b4 + (lr & 3);
        w1h[lr][c] = __float2half(Whh1[gr * HN + c]);
        w2i[lr][c] = __float2half(Wih2[gr * HN + c]);
        w2h[lr][c] = __float2half(Whh2[gr * HN + c]);
    }
    for (int e = tid; e < 4 * HN; e += NTHR) wcol[e] = __float2half(Wih1[e * (FN + 1) + FN]);
    for (int e = tid; e < HN; e += NTHR) wout_s[e] = Wout[e];
    if (tid < 16) {
        int gr = (tid >> 2) * HN + b4 + (tid & 3);
        b1s[tid] = bih1[gr] + bhh1[gr];
        b2s[tid] = bih2[gr] + bhh2[gr];
    }
    if (tid == 0) bouts = bout[0];
    {   // zero h1 (for priming), stage f_0, zero h2 buffer 1 (h2_{-1} = 0)
        int u0 = tid, u1 = tid + NTHR;
        h1p[(u0 >> 5) * 33 + (u0 & 31)] = 0.f;
        h1p[(u1 >> 5) * 33 + (u1 & 31)] = 0.f;
        if (tid < FN) f_p[(tid >> 3) * 9 + (tid & 7)] = feat[tid];
        if (tid < 4) astore(&h2buf[HN + b4 + tid], 0.f);
    }
    __syncthreads();

    // priming: PG1(0) = W_ih1[:, :256] @ f_0 + biases   (h1_{-1}=0)
    {
        int lr = tid >> 5, sub = tid & 31;
        float acc = 0.f;
        #pragma unroll
        for (int k = 0; k < 8; ++k)
            acc += __half2float(w1f[lr][sub * 8 + k]) * f_p[sub * 9 + k];
        #pragma unroll
        for (int m = 1; m <= 16; m <<= 1) acc += __shfl_xor(acc, m);
        if (sub == 0) astore(&pg1buf[(lr >> 2) * HN + b4 + (lr & 3)], acc + b1s[lr]);
    }

    float c1a = 0.f, c1b = 0.f;   // replicated c1 for units tid, tid+512
    float c2v = 0.f;              // c2 for unit b4+tid (tid<4 only)
    float p = tgt[0];             // p0 = targets[0]
    float lacc = 0.f;             // replicated loss accumulator

    if (!gridbar(bar, &s_ok)) return;

    for (int s = 0; s < NSLOT; ++s) {
        const int par = s & 1;
        const int u0 = tid, u1 = tid + NTHR;

        // ---- phase A: load h2(t-1) + PG1(t), stage f(t+1), compute pred(t-1) ----
        float h2v0 = aload(&h2buf[(par ^ 1) * HN + u0]);
        float h2v1 = aload(&h2buf[(par ^ 1) * HN + u1]);
        float pgv[8];
        #pragma unroll
        for (int g = 0; g < 4; ++g) {
            pgv[g]     = aload(&pg1buf[par * 4 * HN + g * HN + u0]);
            pgv[4 + g] = aload(&pg1buf[par * 4 * HN + g * HN + u1]);
        }
        if (tid < FN) f_p[(tid >> 3) * 9 + (tid & 7)] = feat[(s + 1) * FN + tid];
        h2p[(u0 >> 5) * 33 + (u0 & 31)] = h2v0;
        h2p[(u1 >> 5) * 33 + (u1 & 31)] = h2v1;
        float pp = wout_s[u0] * h2v0 + wout_s[u1] * h2v1;
        #pragma unroll
        for (int m = 1; m <= 32; m <<= 1) pp += __shfl_xor(pp, m);
        if ((tid & 63) == 0) rsum[tid >> 6] = pp;
        __syncthreads();
        float dred = rsum[0] + rsum[1] + rsum[2] + rsum[3]
                   + rsum[4] + rsum[5] + rsum[6] + rsum[7];
        if (s > 0) {            // pred_{s-1} = Wout.h2_{s-1} + b_out + p_{s-2}
            p = dred + bouts + p;
            float d = p - tgt[s];
            lacc += d * d;
        }

        // ---- phase B: reconstruct full h1(t) from PG1(t) + p (replicated) ----
        {
            float gi = pgv[0] + p * __half2float(wcol[u0]);
            float gf = pgv[1] + p * __half2float(wcol[HN + u0]);
            float gg = pgv[2] + p * __half2float(wcol[2 * HN + u0]);
            float go = pgv[3] + p * __half2float(wcol[3 * HN + u0]);
            c1a = sigm(gf) * c1a + sigm(gi) * tanh_f(gg);
            h1p[(u0 >> 5) * 33 + (u0 & 31)] = sigm(go) * tanh_f(c1a);
            gi = pgv[4] + p * __half2float(wcol[u1]);
            gf = pgv[5] + p * __half2float(wcol[HN + u1]);
            gg = pgv[6] + p * __half2float(wcol[2 * HN + u1]);
            go = pgv[7] + p * __half2float(wcol[3 * HN + u1]);
            c1b = sigm(gf) * c1b + sigm(gi) * tanh_f(gg);
            h1p[(u1 >> 5) * 33 + (u1 & 31)] = sigm(go) * tanh_f(c1b);
        }
        __syncthreads();

        // ---- phase C: mv1 -> PG1(t+1) slice, mv2 -> gates2(t) slice ----
        {
            int lr = tid >> 5, sub = tid & 31;
            int cc = sub * 32;
            float acc = 0.f;
            #pragma unroll
            for (int k = 0; k < 8; ++k)
                acc += __half2float(w1f[lr][sub * 8 + k]) * f_p[sub * 9 + k];
            #pragma unroll
            for (int k = 0; k < 32; ++k)
                acc += __half2float(w1h[lr][cc + k]) * h1p[sub * 33 + k];
            #pragma unroll
            for (int m = 1; m <= 16; m <<= 1) acc += __shfl_xor(acc, m);
            if (sub == 0)
                astore(&pg1buf[(par ^ 1) * 4 * HN + (lr >> 2) * HN + b4 + (lr & 3)],
                       acc + b1s[lr]);
            float a2 = 0.f;
            #pragma unroll
            for (int k = 0; k < 32; ++k)
                a2 += __half2float(w2i[lr][cc + k]) * h1p[sub * 33 + k];
            #pragma unroll
            for (int k = 0; k < 32; ++k)
                a2 += __half2float(w2h[lr][cc + k]) * h2p[sub * 33 + k];
            #pragma unroll
            for (int m = 1; m <= 16; m <<= 1) a2 += __shfl_xor(a2, m);
            if (sub == 0) g2s[lr] = a2 + b2s[lr];
        }
        __syncthreads();
        if (tid < 4) {   // layer-2 cell update for this block's 4 units
            float gi = sigm(g2s[tid]);
            float gf = sigm(g2s[4 + tid]);
            float gg = tanh_f(g2s[8 + tid]);
            float go = sigm(g2s[12 + tid]);
            c2v = gf * c2v + gi * gg;
            astore(&h2buf[par * HN + b4 + tid], go * tanh_f(c2v));
        }
        if (!gridbar(bar, &s_ok)) return;
    }

    // ---- epilogue: final pred (out[4095]) + loss write ----
    {
        const int par = NSLOT & 1;  // 1
        const int u0 = tid, u1 = tid + NTHR;
        float h2v0 = aload(&h2buf[(par ^ 1) * HN + u0]);
        float h2v1 = aload(&h2buf[(par ^ 1) * HN + u1]);
        float pp = wout_s[u0] * h2v0 + wout_s[u1] * h2v1;
        #pragma unroll
        for (int m = 1; m <= 32; m <<= 1) pp += __shfl_xor(pp, m);
        if ((tid & 63) == 0) rsum[tid >> 6] = pp;
        __syncthreads();
        float dred = rsum[0] + rsum[1] + rsum[2] + rsum[3]
                   + rsum[4] + rsum[5] + rsum[6] + rsum[7];
        p = dred + bouts + p;
        float d = p - tgt[LN - 1];
        lacc += d * d;
        if (blockIdx.x == 0 && tid == 0) out[0] = sqrtf(lacc / (float)LN);
    }
}

extern "C" void kernel_launch(void* const* d_in, const int* in_sizes, int n_in,
                              void* d_out, int out_size, void* d_ws, size_t ws_size,
                              hipStream_t stream) {
    (void)in_sizes; (void)n_in; (void)out_size; (void)ws_size;
    const float* feat = (const float*)d_in[0];
    const float* tgt  = (const float*)d_in[1];
    const float* Wih1 = (const float*)d_in[2];
    const float* bih1 = (const float*)d_in[3];
    const float* Whh1 = (const float*)d_in[4];
    const float* bhh1 = (const float*)d_in[5];
    const float* Wih2 = (const float*)d_in[6];
    const float* bih2 = (const float*)d_in[7];
    const float* Whh2 = (const float*)d_in[8];
    const float* bhh2 = (const float*)d_in[9];
    const float* Wout = (const float*)d_in[10];
    const float* bout = (const float*)d_in[11];
    float* out = (float*)d_out;
    float* ws  = (float*)d_ws;

    unsigned* bar = (unsigned*)(ws + WS_BAR);
    hipLaunchKernelGGL(ws_init, dim3(1), dim3(64), 0, stream, bar);

    const float *a0 = feat, *a1 = tgt, *a2 = Wih1, *a3 = bih1, *a4 = Whh1, *a5 = bhh1,
                *a6 = Wih2, *a7 = bih2, *a8 = Whh2, *a9 = bhh2, *a10 = Wout, *a11 = bout;
    float *a12 = out, *a13 = ws;
    void* args[] = { &a0, &a1, &a2, &a3, &a4, &a5, &a6, &a7, &a8, &a9, &a10, &a11, &a12, &a13 };
    hipError_t e = hipLaunchCooperativeKernel((void*)lstm_main, dim3(NBLK), dim3(NTHR),
                                              args, 0, stream);
    if (e != hipSuccess) {
        // fallback: plain launch (256 blocks x 1 block/CU are co-resident on 256 CUs)
        hipLaunchKernelGGL(lstm_main, dim3(NBLK), dim3(NTHR), 0, stream,
                           feat, tgt, Wih1, bih1, Whh1, bhh1, Wih2, bih2, Whh2, bhh2,
                           Wout, bout, out, ws);
    }
}